// Round 1
// baseline (291.552 us; speedup 1.0000x reference)
//
#include <hip/hip_runtime.h>

// B2B causal depthwise conv, fused single pass.
// x: [B=2, 3*D=12288, L=2048] f32, w_proj: [12288,1,3], w_short: [256,1,7]
// out[b,g,l] = x1[l] * conv7(z)[l],  z = x2*v,
// x1/x2/v = conv3 of input channels 3g / 3g+1 / 3g+2 (interleaved layout).
// conv is cross-correlation with causal (left) zero padding:
//   conv3[l] = w0*x[l-2] + w1*x[l-1] + w2*x[l]
//   conv7[l] = sum_{k=0..6} s_k * z[l-6+k]

constexpr int LSEQ = 2048;
constexpr int DM   = 4096;
constexpr int NT   = 256;    // threads per block; each owns 8 consecutive l
constexpr int NW   = NT / 64;

__global__ __launch_bounds__(NT) void b2b_fused(
    const float* __restrict__ x,
    const float* __restrict__ wproj,
    const float* __restrict__ wshort,
    float* __restrict__ out)
{
    const int bg = blockIdx.x;         // 0 .. 2*4096-1
    const int b  = bg >> 12;
    const int g  = bg & 4095;
    const int t  = threadIdx.x;
    const int wv = t >> 6;
    const int ln = t & 63;

    __shared__ float hx[NW][6];        // wave-boundary x halos (3 rows x 2)
    __shared__ float hz[NW][6];        // wave-boundary z halos (z[2..7] of lane 63)

    // three contiguous input rows: channels 3g, 3g+1, 3g+2
    const size_t rowbase = ((size_t)b * (3 * DM) + (size_t)(3 * g)) * LSEQ;
    const float4* p0 = reinterpret_cast<const float4*>(x + rowbase);
    const float4* p1 = reinterpret_cast<const float4*>(x + rowbase + LSEQ);
    const float4* p2 = reinterpret_cast<const float4*>(x + rowbase + 2 * LSEQ);

    float4 A0 = p0[2 * t], A1 = p0[2 * t + 1];
    float4 B0 = p1[2 * t], B1 = p1[2 * t + 1];
    float4 C0 = p2[2 * t], C1 = p2[2 * t + 1];

    // uniform per-block weights
    const float* wp = wproj + (size_t)(3 * g) * 3;   // 9 consecutive floats
    const float w00 = wp[0], w01 = wp[1], w02 = wp[2];
    const float w10 = wp[3], w11 = wp[4], w12 = wp[5];
    const float w20 = wp[6], w21 = wp[7], w22 = wp[8];
    const float* ws = wshort + (size_t)(g >> 4) * 7; // filter shared per 16 channels
    const float s0 = ws[0], s1 = ws[1], s2 = ws[2], s3 = ws[3],
                s4 = ws[4], s5 = ws[5], s6 = ws[6];

    // publish wave-boundary x halos (last 2 elements of each row in lane 63)
    if (ln == 63) {
        hx[wv][0] = A1.z; hx[wv][1] = A1.w;
        hx[wv][2] = B1.z; hx[wv][3] = B1.w;
        hx[wv][4] = C1.z; hx[wv][5] = C1.w;
    }
    __syncthreads();

    // halo = elements l0-2, l0-1 of each row, from lane t-1 (or LDS / zero)
    float ha0 = __shfl_up(A1.z, 1), ha1 = __shfl_up(A1.w, 1);
    float hb0 = __shfl_up(B1.z, 1), hb1 = __shfl_up(B1.w, 1);
    float hc0 = __shfl_up(C1.z, 1), hc1 = __shfl_up(C1.w, 1);
    if (ln == 0) {
        if (wv == 0) {
            ha0 = ha1 = hb0 = hb1 = hc0 = hc1 = 0.f;  // causal zero pad
        } else {
            ha0 = hx[wv - 1][0]; ha1 = hx[wv - 1][1];
            hb0 = hx[wv - 1][2]; hb1 = hx[wv - 1][3];
            hc0 = hx[wv - 1][4]; hc1 = hx[wv - 1][5];
        }
    }

    // extended rows: index i holds x[l0 - 2 + i]
    float X0[10] = {ha0, ha1, A0.x, A0.y, A0.z, A0.w, A1.x, A1.y, A1.z, A1.w};
    float X1[10] = {hb0, hb1, B0.x, B0.y, B0.z, B0.w, B1.x, B1.y, B1.z, B1.w};
    float X2[10] = {hc0, hc1, C0.x, C0.y, C0.z, C0.w, C1.x, C1.y, C1.z, C1.w};

    float x1v[8], z[8];
#pragma unroll
    for (int e = 0; e < 8; ++e) {
        float a  = fmaf(w00, X0[e], fmaf(w01, X0[e + 1], w02 * X0[e + 2]));
        float x2 = fmaf(w10, X1[e], fmaf(w11, X1[e + 1], w12 * X1[e + 2]));
        float vv = fmaf(w20, X2[e], fmaf(w21, X2[e + 1], w22 * X2[e + 2]));
        x1v[e] = a;
        z[e]   = x2 * vv;
    }

    // publish wave-boundary z halos (z[2..7] of lane 63)
    if (ln == 63) {
#pragma unroll
        for (int k = 0; k < 6; ++k) hz[wv][k] = z[2 + k];
    }
    __syncthreads();

    // z halo: previous thread's z[2..7] == z at l0-6 .. l0-1
    float zh[6];
#pragma unroll
    for (int k = 0; k < 6; ++k) zh[k] = __shfl_up(z[2 + k], 1);
    if (ln == 0) {
        if (wv == 0) {
#pragma unroll
            for (int k = 0; k < 6; ++k) zh[k] = 0.f;   // causal zero pad
        } else {
#pragma unroll
            for (int k = 0; k < 6; ++k) zh[k] = hz[wv - 1][k];
        }
    }

    // extended z: index i holds z[l0 - 6 + i]
    float EZ[14] = {zh[0], zh[1], zh[2], zh[3], zh[4], zh[5],
                    z[0], z[1], z[2], z[3], z[4], z[5], z[6], z[7]};

    float o[8];
#pragma unroll
    for (int e = 0; e < 8; ++e) {
        float acc = s0 * EZ[e];
        acc = fmaf(s1, EZ[e + 1], acc);
        acc = fmaf(s2, EZ[e + 2], acc);
        acc = fmaf(s3, EZ[e + 3], acc);
        acc = fmaf(s4, EZ[e + 4], acc);
        acc = fmaf(s5, EZ[e + 5], acc);
        acc = fmaf(s6, EZ[e + 6], acc);
        o[e] = x1v[e] * acc;
    }

    float4* po = reinterpret_cast<float4*>(out + ((size_t)b * DM + g) * LSEQ);
    po[2 * t]     = make_float4(o[0], o[1], o[2], o[3]);
    po[2 * t + 1] = make_float4(o[4], o[5], o[6], o[7]);
}

extern "C" void kernel_launch(void* const* d_in, const int* in_sizes, int n_in,
                              void* d_out, int out_size, void* d_ws, size_t ws_size,
                              hipStream_t stream) {
    const float* x      = (const float*)d_in[0];
    const float* wproj  = (const float*)d_in[1];
    const float* wshort = (const float*)d_in[2];
    float* out          = (float*)d_out;

    dim3 grid(2 * 4096);   // one block per (b, g)
    b2b_fused<<<grid, NT, 0, stream>>>(x, wproj, wshort, out);
}

// Round 3
// 291.482 us; speedup vs baseline: 1.0002x; 1.0002x over previous
//
#include <hip/hip_runtime.h>

// B2B causal depthwise conv, fused single pass, zero-LDS / zero-barrier.
// x: [B=2, 3*D=12288, L=2048] f32, w_proj: [12288,1,3], w_short: [256,1,7]
// out[b,g,l] = x1[l] * conv7(z)[l],  z = x2*v
// x1/x2/v = causal conv3 of input channels 3g / 3g+1 / 3g+2 (interleaved).
//   conv3[l] = w0*x[l-2] + w1*x[l-1] + w2*x[l]
//   conv7[l] = sum_{k=0..6} s_k * z[l-6+k]
//
// Each thread owns 8 consecutive l. Halos come from lane t-1 via __shfl_up;
// wave-leading lanes (ln==0, t>0) re-fetch the few boundary values from
// global (L2-hot: the neighboring wave just streamed those lines) and
// recompute the 6 z-halo values locally. Sequence start (t==0) is zero-pad.

constexpr int LSEQ = 2048;
constexpr int DM   = 4096;
constexpr int NT   = 256;    // threads per block; each owns 8 consecutive l

typedef float f4 __attribute__((ext_vector_type(4)));

__global__ __launch_bounds__(NT) void b2b_fused(
    const float* __restrict__ x,
    const float* __restrict__ wproj,
    const float* __restrict__ wshort,
    float* __restrict__ out)
{
    const int bg = blockIdx.x;         // 0 .. 2*4096-1
    const int b  = bg >> 12;
    const int g  = bg & 4095;
    const int t  = threadIdx.x;
    const int ln = t & 63;
    const int l0 = t << 3;             // first l owned by this thread

    // three contiguous input rows: channels 3g, 3g+1, 3g+2
    const size_t rowbase = ((size_t)b * (3 * DM) + (size_t)(3 * g)) * LSEQ;
    const f4* p0 = reinterpret_cast<const f4*>(x + rowbase);
    const f4* p1 = reinterpret_cast<const f4*>(x + rowbase + LSEQ);
    const f4* p2 = reinterpret_cast<const f4*>(x + rowbase + 2 * LSEQ);

    f4 A0 = __builtin_nontemporal_load(p0 + 2 * t);
    f4 A1 = __builtin_nontemporal_load(p0 + 2 * t + 1);
    f4 B0 = __builtin_nontemporal_load(p1 + 2 * t);
    f4 B1 = __builtin_nontemporal_load(p1 + 2 * t + 1);
    f4 C0 = __builtin_nontemporal_load(p2 + 2 * t);
    f4 C1 = __builtin_nontemporal_load(p2 + 2 * t + 1);

    // block-uniform weights (scalar loads)
    const float* wp = wproj + (size_t)(3 * g) * 3;   // 9 consecutive floats
    const float w00 = wp[0], w01 = wp[1], w02 = wp[2];
    const float w10 = wp[3], w11 = wp[4], w12 = wp[5];
    const float w20 = wp[6], w21 = wp[7], w22 = wp[8];
    const float* ws = wshort + (size_t)(g >> 4) * 7; // shared per 16 channels
    const float s0 = ws[0], s1 = ws[1], s2 = ws[2], s3 = ws[3],
                s4 = ws[4], s5 = ws[5], s6 = ws[6];

    // wave-internal x halos (elements l0-2, l0-1 of each row) from lane-1
    float ha0 = __shfl_up(A1.z, 1), ha1 = __shfl_up(A1.w, 1);
    float hb0 = __shfl_up(B1.z, 1), hb1 = __shfl_up(B1.w, 1);
    float hc0 = __shfl_up(C1.z, 1), hc1 = __shfl_up(C1.w, 1);

    float zh[6];                        // z at l0-6 .. l0-1 (edge lanes only)
    const bool edge = (ln == 0);
    if (edge) {
        if (t == 0) {
            ha0 = ha1 = hb0 = hb1 = hc0 = hc1 = 0.f;   // causal zero pad
#pragma unroll
            for (int k = 0; k < 6; ++k) zh[k] = 0.f;
        } else {
            // boundary values from global (L2-hot lines)
            const int q = (l0 - 8) >> 2;               // f4 index of l0-8
            f4 E0  = p0[q + 1];                        // row0[l0-4 .. l0-1]
            f4 D1a = p1[q], D1b = p1[q + 1];           // row1[l0-8 .. l0-1]
            f4 D2a = p2[q], D2b = p2[q + 1];           // row2[l0-8 .. l0-1]
            ha0 = E0.z;  ha1 = E0.w;
            hb0 = D1b.z; hb1 = D1b.w;
            hc0 = D2b.z; hc1 = D2b.w;
            float R1[8] = {D1a.x, D1a.y, D1a.z, D1a.w, D1b.x, D1b.y, D1b.z, D1b.w};
            float R2[8] = {D2a.x, D2a.y, D2a.z, D2a.w, D2b.x, D2b.y, D2b.z, D2b.w};
#pragma unroll
            for (int k = 0; k < 6; ++k) {              // z[l0-6+k]
                float x2h = fmaf(w10, R1[k], fmaf(w11, R1[k + 1], w12 * R1[k + 2]));
                float vh  = fmaf(w20, R2[k], fmaf(w21, R2[k + 1], w22 * R2[k + 2]));
                zh[k] = x2h * vh;
            }
        }
    }

    // extended rows: index i holds x[l0 - 2 + i]
    float X0[10] = {ha0, ha1, A0.x, A0.y, A0.z, A0.w, A1.x, A1.y, A1.z, A1.w};
    float X1[10] = {hb0, hb1, B0.x, B0.y, B0.z, B0.w, B1.x, B1.y, B1.z, B1.w};
    float X2[10] = {hc0, hc1, C0.x, C0.y, C0.z, C0.w, C1.x, C1.y, C1.z, C1.w};

    float x1v[8], z[8];
#pragma unroll
    for (int e = 0; e < 8; ++e) {
        float a  = fmaf(w00, X0[e], fmaf(w01, X0[e + 1], w02 * X0[e + 2]));
        float x2 = fmaf(w10, X1[e], fmaf(w11, X1[e + 1], w12 * X1[e + 2]));
        float vv = fmaf(w20, X2[e], fmaf(w21, X2[e + 1], w22 * X2[e + 2]));
        x1v[e] = a;
        z[e]   = x2 * vv;
    }

    // z halo for non-edge lanes: previous lane's z[2..7] == z[l0-6 .. l0-1]
#pragma unroll
    for (int k = 0; k < 6; ++k) {
        float zs = __shfl_up(z[2 + k], 1);   // wave-uniform execution
        zh[k] = edge ? zh[k] : zs;
    }

    // extended z: index i holds z[l0 - 6 + i]
    float EZ[14] = {zh[0], zh[1], zh[2], zh[3], zh[4], zh[5],
                    z[0], z[1], z[2], z[3], z[4], z[5], z[6], z[7]};

    f4 O0, O1;
#pragma unroll
    for (int e = 0; e < 8; ++e) {
        float acc = s0 * EZ[e];
        acc = fmaf(s1, EZ[e + 1], acc);
        acc = fmaf(s2, EZ[e + 2], acc);
        acc = fmaf(s3, EZ[e + 3], acc);
        acc = fmaf(s4, EZ[e + 4], acc);
        acc = fmaf(s5, EZ[e + 5], acc);
        acc = fmaf(s6, EZ[e + 6], acc);
        float o = x1v[e] * acc;
        if (e < 4) { ((float*)&O0)[e] = o; } else { ((float*)&O1)[e - 4] = o; }
    }

    f4* po = reinterpret_cast<f4*>(out + ((size_t)b * DM + g) * LSEQ);
    __builtin_nontemporal_store(O0, po + 2 * t);
    __builtin_nontemporal_store(O1, po + 2 * t + 1);
}

extern "C" void kernel_launch(void* const* d_in, const int* in_sizes, int n_in,
                              void* d_out, int out_size, void* d_ws, size_t ws_size,
                              hipStream_t stream) {
    const float* x      = (const float*)d_in[0];
    const float* wproj  = (const float*)d_in[1];
    const float* wshort = (const float*)d_in[2];
    float* out          = (float*)d_out;

    dim3 grid(2 * 4096);   // one block per (b, g)
    b2b_fused<<<grid, NT, 0, stream>>>(x, wproj, wshort, out);
}